// Round 15
// baseline (1085.820 us; speedup 1.0000x reference)
//
#include <hip/hip_runtime.h>

#define NN 100000
#define EE 1600000
#define GG 512
#define LL 5
#define HID 64
#define RCOLS (HID*LL)   // 320
#define OUTC 16
#define NGRP ((NN + 63) / 64)     // 1563
#define NBUCK ((NN + 255) / 256)  // 391 buckets of 256 nodes
#define BCAP 4864                 // bucket capacity: mean 4096 + 12 sigma
#define SEGSZ 25600               // 4 source segments -> Y seg = 3.28MB < 4MB L2

typedef unsigned int uint;
typedef unsigned short ushort;
typedef __attribute__((ext_vector_type(8))) short short8;
typedef __attribute__((ext_vector_type(4))) float f32x4;

__device__ __forceinline__ float bf2f(ushort u) {
    return __uint_as_float(((uint)u) << 16);
}
__device__ __forceinline__ ushort f2bf(float f) {
    uint u = __float_as_uint(f);
    u = (u + 0x7fffu + ((u >> 16) & 1u)) >> 16;   // round-to-nearest-even
    return (ushort)u;
}
__device__ __forceinline__ uint pack2(float a, float b) {
    return (uint)f2bf(a) | ((uint)f2bf(b) << 16);
}
__device__ __forceinline__ float lo16(uint p) { return __uint_as_float(p << 16); }
__device__ __forceinline__ float hi16(uint p) { return __uint_as_float(p & 0xffff0000u); }

// ================= bucketed CSR build, fixed-capacity buckets =================
__global__ __launch_bounds__(256) void init_bcur_kernel(int* __restrict__ bcur)
{
    int i = blockIdx.x * 256 + threadIdx.x;
    if (i < NBUCK) bcur[i] = i * BCAP;
}

__global__ __launch_bounds__(256) void binfill_kernel(
    const int* __restrict__ src, const int* __restrict__ dst,
    int* __restrict__ bcur, uint* __restrict__ bin)
{
    __shared__ int hcnt[NBUCK], hbase[NBUCK];
    const int tid = threadIdx.x;
    for (int b = tid; b < NBUCK; b += 256) hcnt[b] = 0;
    __syncthreads();
    const int chunk = (EE + gridDim.x - 1) / gridDim.x;
    const int e0 = blockIdx.x * chunk;
    const int e1 = (e0 + chunk < EE) ? e0 + chunk : EE;
    for (int e = e0 + tid; e < e1; e += 256)
        atomicAdd(&hcnt[dst[e] >> 8], 1);
    __syncthreads();
    for (int b = tid; b < NBUCK; b += 256) {
        int c = hcnt[b];
        hbase[b] = c ? atomicAdd(&bcur[b], c) : 0;
        hcnt[b] = 0;
    }
    __syncthreads();
    for (int e = e0 + tid; e < e1; e += 256) {
        int d = dst[e];
        int b = d >> 8;
        int off = atomicAdd(&hcnt[b], 1);
        bin[hbase[b] + off] = ((uint)src[e] << 8) | (uint)(d & 255);   // src<2^24
    }
}

// per-bucket: per-(node,seg) LDS hist -> scan -> rowseg4/rowend; seg-partitioned scatter
__global__ __launch_bounds__(256) void bucket_csr_kernel(
    const uint* __restrict__ bin, const int* __restrict__ bcur,
    int4* __restrict__ rowseg4, int* __restrict__ rowend, int* __restrict__ col)
{
    __shared__ int h4[256][4];
    __shared__ int s[256];
    __shared__ int c4[256][4];
    const int b = blockIdx.x;
    const int tid = threadIdx.x;
    const int base = b * BCAP;
    const int cnt = bcur[b] - base;
    h4[tid][0] = 0; h4[tid][1] = 0; h4[tid][2] = 0; h4[tid][3] = 0;
    __syncthreads();
    for (int i = tid; i < cnt; i += 256) {
        uint w = bin[base + i];
        int srcv = (int)(w >> 8);
        atomicAdd(&h4[w & 255][srcv / SEGSZ], 1);
    }
    __syncthreads();
    const int t0 = h4[tid][0], t1 = h4[tid][1], t2 = h4[tid][2], t3 = h4[tid][3];
    const int own = t0 + t1 + t2 + t3;
    s[tid] = own;
    __syncthreads();
    int val = own;
    for (int off = 1; off < 256; off <<= 1) {
        int other = (tid >= off) ? s[tid - off] : 0;
        __syncthreads();
        val += other;
        s[tid] = val;
        __syncthreads();
    }
    const int nb = base + (val - own);
    const int node = b * 256 + tid;
    if (node < NN) {
        rowseg4[node] = make_int4(nb, nb + t0, nb + t0 + t1, nb + t0 + t1 + t2);
        rowend[node] = nb + own;
    }
    c4[tid][0] = nb; c4[tid][1] = nb + t0; c4[tid][2] = nb + t0 + t1; c4[tid][3] = nb + t0 + t1 + t2;
    __syncthreads();
    for (int i = tid; i < cnt; i += 256) {
        uint w = bin[base + i];
        int srcv = (int)(w >> 8);
        int p = atomicAdd(&c4[w & 255][srcv / SEGSZ], 1);
        col[p] = srcv;
    }
}

// -------- prep: transposed bf16 weights, [c][72] padded rows, L1-resident at use --------
__global__ __launch_bounds__(256) void prep_w_kernel(
    const float* __restrict__ W2, const float* __restrict__ W1_r,
    ushort* __restrict__ w2t, ushort* __restrict__ w1nt)
{
    const int i = blockIdx.x * 256 + threadIdx.x;
    if (i < 5 * 4096) {
        int l = i >> 12, r = i & 4095, k = r >> 6, c = r & 63;
        w2t[l * 4608 + c * 72 + k] = f2bf(W2[l * 4096 + k * 64 + c]);
    }
    if (i < 4 * 4096) {
        int l = i >> 12, r = i & 4095, k = r >> 6, c = r & 63;
        w1nt[l * 4608 + c * 72 + k] = f2bf(W1_r[l * 4096 + k * 64 + c]);
    }
}

// ---------------- y0 = x @ W1_0  (fp32 [N,128] @ [128,64] -> bf16 [N,64]) ----------------
__global__ __launch_bounds__(256) void ingemm_kernel(
    const float* __restrict__ x, const float* __restrict__ W1,
    ushort* __restrict__ Y0)
{
    __shared__ __align__(16) ushort W1t[64 * 136];
    __shared__ __align__(16) ushort zA[4][16 * 72];

    for (int e = threadIdx.x; e < 64 * 128; e += 256) {
        int c = e & 63, k = e >> 6;
        W1t[c * 136 + k] = f2bf(W1[k * 64 + c]);
    }
    __syncthreads();

    const int lane = threadIdx.x & 63;
    const int wave = threadIdx.x >> 6;
    const int fr = lane & 15, fq = lane >> 4;
    ushort* zw = zA[wave];

    for (int grp = blockIdx.x; grp < NGRP; grp += gridDim.x) {
        const int base = grp * 64 + wave * 16;
        if (base >= NN) continue;

        short8 az[4];
        #pragma unroll
        for (int h = 0; h < 4; ++h) {
            const float* xp = x + (size_t)(base + fr) * 128 + h * 32 + fq * 8;
            float4 f0 = *(const float4*)xp;
            float4 f1 = *(const float4*)(xp + 4);
            short8 a;
            a[0] = (short)f2bf(f0.x); a[1] = (short)f2bf(f0.y);
            a[2] = (short)f2bf(f0.z); a[3] = (short)f2bf(f0.w);
            a[4] = (short)f2bf(f1.x); a[5] = (short)f2bf(f1.y);
            a[6] = (short)f2bf(f1.z); a[7] = (short)f2bf(f1.w);
            az[h] = a;
        }
        #pragma unroll
        for (int t = 0; t < 4; ++t) {
            f32x4 acc = {0.f, 0.f, 0.f, 0.f};
            #pragma unroll
            for (int h = 0; h < 4; ++h) {
                short8 bw = *(const short8*)&W1t[(t * 16 + fr) * 136 + h * 32 + fq * 8];
                acc = __builtin_amdgcn_mfma_f32_16x16x32_bf16(az[h], bw, acc, 0, 0, 0);
            }
            #pragma unroll
            for (int r = 0; r < 4; ++r)
                zw[(fq * 4 + r) * 72 + t * 16 + fr] = f2bf(acc[r]);
        }
        #pragma unroll 4
        for (int i = 0; i < 16; ++i)
            Y0[(size_t)(base + i) * 64 + lane] = zw[i * 72 + lane];
    }
}

// ------- fused layer, SEGMENT-PHASED gather (R15):
// outer loop over 4 source segments (Y-seg 3.28MB, L2-resident per phase; all
// co-resident waves sweep segments in lockstep since block work is ~uniform).
// Per-pair fp32 accumulators for all 8 pairs live in registers across phases.
template<bool LAST>
__global__ __launch_bounds__(256, 6) void gin_layer_kernel(
    const ushort* __restrict__ Y,
    const int4* __restrict__ rowseg4, const int* __restrict__ rowend,
    const int* __restrict__ col,
    const float* __restrict__ eps_arr, int l,
    const float* __restrict__ b1,
    const ushort* __restrict__ w2t,    // bf16 [64][72] W2^T
    const float* __restrict__ b2,
    const float* __restrict__ g_a, const float* __restrict__ be_a,
    const float* __restrict__ m_a, const float* __restrict__ v_a,
    const float* __restrict__ g_b, const float* __restrict__ be_b,
    const float* __restrict__ m_b, const float* __restrict__ v_b,
    const ushort* __restrict__ w1nt,   // bf16 [64][72] W1next^T (unused if LAST)
    const int* __restrict__ batch,
    ushort* __restrict__ Ynext,
    float* __restrict__ readout,
    int layer_off)
{
    __shared__ __align__(16) ushort zA[4][16 * 72];   // per-wave tile [r][k]
    __shared__ float2 bnA[64], bnB[64];
    __shared__ __align__(16) int idxs[4][144];        // [72 rowA | 72 rowB], pads=NN

    if (threadIdx.x < 64) {
        int c = threadIdx.x;
        float sa = g_a[c] * rsqrtf(v_a[c] + 1e-5f);
        float sb = g_b[c] * rsqrtf(v_b[c] + 1e-5f);
        bnA[c] = make_float2(sa, be_a[c] + (b1[c] - m_a[c]) * sa);
        bnB[c] = make_float2(sb, be_b[c] + (b2[c] - m_b[c]) * sb);
    }
    const float eps_l = 1.0f + eps_arr[l];
    __syncthreads();

    const int lane = threadIdx.x & 63;
    const int wave = threadIdx.x >> 6;
    const int fr = lane & 15, fq = lane >> 4;
    const int c4c = (lane & 15) * 4;       // channel base (4 channels per lane)
    const int sl = (lane >> 4) & 1;        // neighbor slot within half
    const int rb = (lane >> 5) * 72;       // idw base: 0=row A half, 72=row B half
    ushort* zw = zA[wave];
    int* idw = idxs[wave];
    const float2 ba0 = bnA[c4c], ba1 = bnA[c4c + 1], ba2 = bnA[c4c + 2], ba3 = bnA[c4c + 3];

    for (int grp = blockIdx.x; grp < NGRP; grp += gridDim.x) {
        const int base = grp * 64 + wave * 16;
        if (base >= NN) continue;      // NN%16==0: waves all-valid or all-idle

        float ac[8][4];
        #pragma unroll
        for (int p = 0; p < 8; ++p) { ac[p][0] = 0.f; ac[p][1] = 0.f; ac[p][2] = 0.f; ac[p][3] = 0.f; }

        // ---- phase 1: segment-phased gather (all waves on seg s together) ----
        for (int s = 0; s < 4; ++s) {
            #pragma unroll
            for (int p = 0; p < 8; ++p) {
                const int rowA = base + 2 * p, rowB = rowA + 1;
                int4 rA = rowseg4[rowA];
                int4 rBv = rowseg4[rowB];
                int eA = rowend[rowA];
                int eB = rowend[rowB];
                int ja  = s == 0 ? rA.x  : s == 1 ? rA.y  : s == 2 ? rA.z  : rA.w;
                int reA = s == 0 ? rA.y  : s == 1 ? rA.z  : s == 2 ? rA.w  : eA;
                int jb  = s == 0 ? rBv.x : s == 1 ? rBv.y : s == 2 ? rBv.z : rBv.w;
                int reB = s == 0 ? rBv.y : s == 1 ? rBv.z : s == 2 ? rBv.w : eB;
                while (ja < reA || jb < reB) {
                    int cntA = reA - ja; cntA = cntA > 64 ? 64 : cntA;
                    int cntB = reB - jb; cntB = cntB > 64 ? 64 : cntB;
                    {
                        int ia = ja + (lane < cntA ? lane : 0);
                        int ca = col[ia];
                        idw[lane] = (lane < cntA) ? ca : NN;
                        int ib = jb + (lane < cntB ? lane : 0);
                        int cb = col[ib];
                        idw[72 + lane] = (lane < cntB) ? cb : NN;
                        if (lane < 8) { idw[64 + lane] = NN; idw[136 + lane] = NN; }
                    }
                    const int niA = (cntA + 1) >> 1, niB = (cntB + 1) >> 1;
                    const int ni = niA > niB ? niA : niB;
                    for (int t = 0; t < ni; t += 4) {
                        int r0 = idw[rb + (t + 0) * 2 + sl];
                        int r1 = idw[rb + (t + 1) * 2 + sl];
                        int r2 = idw[rb + (t + 2) * 2 + sl];
                        int r3 = idw[rb + (t + 3) * 2 + sl];
                        uint2 w0 = *(const uint2*)&Y[(size_t)r0 * 64 + c4c];
                        uint2 w1 = *(const uint2*)&Y[(size_t)r1 * 64 + c4c];
                        uint2 w2 = *(const uint2*)&Y[(size_t)r2 * 64 + c4c];
                        uint2 w3 = *(const uint2*)&Y[(size_t)r3 * 64 + c4c];
                        ac[p][0] += (lo16(w0.x) + lo16(w1.x)) + (lo16(w2.x) + lo16(w3.x));
                        ac[p][1] += (hi16(w0.x) + hi16(w1.x)) + (hi16(w2.x) + hi16(w3.x));
                        ac[p][2] += (lo16(w0.y) + lo16(w1.y)) + (lo16(w2.y) + lo16(w3.y));
                        ac[p][3] += (hi16(w0.y) + hi16(w1.y)) + (hi16(w2.y) + hi16(w3.y));
                    }
                    ja += cntA; jb += cntB;
                }
            }
        }

        // ---- per-pair epilogue: slot combine, self row, BN, ReLU, zw write ----
        #pragma unroll
        for (int p = 0; p < 8; ++p) {
            const int i = 2 * p;
            const int rowA = base + i, rowB = rowA + 1;
            float a0 = ac[p][0], a1 = ac[p][1], a2 = ac[p][2], a3 = ac[p][3];
            a0 += __shfl_xor(a0, 16); a1 += __shfl_xor(a1, 16);
            a2 += __shfl_xor(a2, 16); a3 += __shfl_xor(a3, 16);
            const int myrow = (lane < 32) ? rowA : rowB;
            uint2 wr = *(const uint2*)&Y[(size_t)myrow * 64 + c4c];
            a0 += eps_l * lo16(wr.x); a1 += eps_l * hi16(wr.x);
            a2 += eps_l * lo16(wr.y); a3 += eps_l * hi16(wr.y);
            float z0 = fmaxf(a0 * ba0.x + ba0.y, 0.f);
            float z1 = fmaxf(a1 * ba1.x + ba1.y, 0.f);
            float z2 = fmaxf(a2 * ba2.x + ba2.y, 0.f);
            float z3 = fmaxf(a3 * ba3.x + ba3.y, 0.f);
            if ((lane & 31) < 16) {    // lanes 0-15 write rowA, 32-47 write rowB
                uint2 pz;
                pz.x = pack2(z0, z1);
                pz.y = pack2(z2, z3);
                *(uint2*)&zw[(i + (lane >> 5)) * 72 + c4c] = pz;
            }
        }

        // ---- phase 2: v2 = relu(bnB(v1 @ W2)) -> zw ----
        short8 a2f[2];
        a2f[0] = *(const short8*)&zw[fr * 72 + fq * 8];
        a2f[1] = *(const short8*)&zw[fr * 72 + 32 + fq * 8];
        #pragma unroll
        for (int t = 0; t < 4; ++t) {
            f32x4 acc = {0.f, 0.f, 0.f, 0.f};
            short8 bw0 = *(const short8*)&w2t[(t * 16 + fr) * 72 + fq * 8];
            short8 bw1 = *(const short8*)&w2t[(t * 16 + fr) * 72 + 32 + fq * 8];
            acc = __builtin_amdgcn_mfma_f32_16x16x32_bf16(a2f[0], bw0, acc, 0, 0, 0);
            acc = __builtin_amdgcn_mfma_f32_16x16x32_bf16(a2f[1], bw1, acc, 0, 0, 0);
            float2 bn = bnB[t * 16 + fr];
            #pragma unroll
            for (int r = 0; r < 4; ++r) {
                float v = fmaxf(acc[r] * bn.x + bn.y, 0.f);
                zw[(fq * 4 + r) * 72 + t * 16 + fr] = f2bf(v);
            }
        }

        // ---- phase 3: run-length-reduced readout atomics ----
        {
            int curg = batch[base];
            float racc = 0.f;
            #pragma unroll 4
            for (int i = 0; i < 16; ++i) {
                const float v = bf2f(zw[i * 72 + lane]);
                const int g = batch[base + i];
                if (g != curg) {   // wave-uniform (batch sorted)
                    unsafeAtomicAdd(readout + (size_t)curg * RCOLS + layer_off + lane, racc);
                    curg = g;
                    racc = v;
                } else {
                    racc += v;
                }
            }
            unsafeAtomicAdd(readout + (size_t)curg * RCOLS + layer_off + lane, racc);
        }

        // ---- phase 4: Ynext = v2 @ W1next; coalesced row stores ----
        if constexpr (!LAST) {
            short8 a3f[2];
            a3f[0] = *(const short8*)&zw[fr * 72 + fq * 8];
            a3f[1] = *(const short8*)&zw[fr * 72 + 32 + fq * 8];
            #pragma unroll
            for (int t = 0; t < 4; ++t) {
                f32x4 acc = {0.f, 0.f, 0.f, 0.f};
                short8 bw0 = *(const short8*)&w1nt[(t * 16 + fr) * 72 + fq * 8];
                short8 bw1 = *(const short8*)&w1nt[(t * 16 + fr) * 72 + 32 + fq * 8];
                acc = __builtin_amdgcn_mfma_f32_16x16x32_bf16(a3f[0], bw0, acc, 0, 0, 0);
                acc = __builtin_amdgcn_mfma_f32_16x16x32_bf16(a3f[1], bw1, acc, 0, 0, 0);
                #pragma unroll
                for (int r = 0; r < 4; ++r)
                    zw[(fq * 4 + r) * 72 + t * 16 + fr] = f2bf(acc[r]);
            }
            #pragma unroll 4
            for (int i = 0; i < 16; ++i)
                Ynext[(size_t)(base + i) * 64 + lane] = zw[i * 72 + lane];
        }
    }
}

// ---------------- final graph-level GEMM: [G,320] @ [320,16] + bc ----------------
__global__ __launch_bounds__(256) void final_gemm(
    const float* __restrict__ R, const float* __restrict__ Wc,
    const float* __restrict__ bc, float* __restrict__ out)
{
    const int tid = blockIdx.x * 256 + threadIdx.x;
    if (tid >= GG * OUTC) return;
    const int g = tid >> 4;
    const int o = tid & 15;
    float acc = bc[o];
    const float* r = R + (size_t)g * RCOLS;
    #pragma unroll 8
    for (int k = 0; k < RCOLS; ++k)
        acc += r[k] * Wc[k * OUTC + o];
    out[tid] = acc;
}

extern "C" void kernel_launch(void* const* d_in, const int* in_sizes, int n_in,
                              void* d_out, int out_size, void* d_ws, size_t ws_size,
                              hipStream_t stream)
{
    const float* x    = (const float*)d_in[0];
    const int*   ei   = (const int*)d_in[1];
    const int*   batch= (const int*)d_in[2];
    const float* eps  = (const float*)d_in[3];
    const float* W1_0 = (const float*)d_in[4];
    const float* b1_0 = (const float*)d_in[5];
    const float* W1_r = (const float*)d_in[6];
    const float* b1_r = (const float*)d_in[7];
    const float* g_a  = (const float*)d_in[8];
    const float* be_a = (const float*)d_in[9];
    const float* m_a  = (const float*)d_in[10];
    const float* v_a  = (const float*)d_in[11];
    const float* W2   = (const float*)d_in[12];
    const float* b2   = (const float*)d_in[13];
    const float* g_b  = (const float*)d_in[14];
    const float* be_b = (const float*)d_in[15];
    const float* m_b  = (const float*)d_in[16];
    const float* v_b  = (const float*)d_in[17];
    const float* Wc   = (const float*)d_in[18];
    const float* bc   = (const float*)d_in[19];
    float* out = (float*)d_out;

    const int* src = ei;
    const int* dst = ei + EE;

    // workspace layout (bytes); y_b ALIASES bin (bin dead after bucket_csr,
    // y_b first written by layer0 which runs after). y rows NN = zero pad.
    char* ws = (char*)d_ws;
    int4*   rowseg4 = (int4*)(ws);                       // N*16 = 1.6MB
    int*    rowend  = (int*)(ws + 1638400);              // N*4
    int*    bcur    = (int*)(ws + 2097152);              // NBUCK*4
    int*    col     = (int*)(ws + 2621440);              // NBUCK*BCAP*4 = 7.61MB
    uint*   bin     = (uint*)(ws + 10485760);            // 7.61MB (aliased by y_b)
    ushort* y_b     = (ushort*)(ws + 10485760);          // (N+1)*128 = 12.81MB
    ushort* y_a     = (ushort*)(ws + 23592960);          // 12.81MB
    float*  readout = (float*)(ws + 36700160);           // 640KB
    ushort* w2t_g   = (ushort*)(ws + 37748736);          // 46080
    ushort* w1nt_g  = (ushort*)(ws + 37812224);          // 36864

    hipMemsetAsync(readout, 0, (size_t)GG * RCOLS * 4, stream);
    hipMemsetAsync(y_a + (size_t)NN * 64, 0, 128, stream);   // zero pad-row
    hipMemsetAsync(y_b + (size_t)NN * 64, 0, 128, stream);   // beyond bin extent

    init_bcur_kernel<<<(NBUCK + 255) / 256, 256, 0, stream>>>(bcur);
    prep_w_kernel<<<80, 256, 0, stream>>>(W2, W1_r, w2t_g, w1nt_g);
    ingemm_kernel<<<NGRP, 256, 0, stream>>>(x, W1_0, y_a);   // y0 = x @ W1_0
    binfill_kernel<<<256, 256, 0, stream>>>(src, dst, bcur, bin);
    bucket_csr_kernel<<<NBUCK, 256, 0, stream>>>(bin, bcur, rowseg4, rowend, col);

    ushort* y_cur = y_a;
    ushort* y_nxt = y_b;

    for (int l = 0; l < LL; ++l) {
        const float* b1 = (l == 0) ? b1_0 : (b1_r + (size_t)(l - 1) * 64);
        const int off = l * 64;
        const ushort* w2t  = w2t_g + (size_t)l * 4608;
        const ushort* w1nt = (l < LL - 1) ? (w1nt_g + (size_t)l * 4608) : w1nt_g;
        if (l < LL - 1) {
            gin_layer_kernel<false><<<NGRP, 256, 0, stream>>>(
                y_cur, rowseg4, rowend, col, eps, l, b1,
                w2t, b2 + off,
                g_a + off, be_a + off, m_a + off, v_a + off,
                g_b + off, be_b + off, m_b + off, v_b + off,
                w1nt, batch, y_nxt, readout, off);
        } else {
            gin_layer_kernel<true><<<NGRP, 256, 0, stream>>>(
                y_cur, rowseg4, rowend, col, eps, l, b1,
                w2t, b2 + off,
                g_a + off, be_a + off, m_a + off, v_a + off,
                g_b + off, be_b + off, m_b + off, v_b + off,
                w1nt, batch, y_nxt, readout, off);
        }
        ushort* t = y_cur; y_cur = y_nxt; y_nxt = t;
    }

    final_gemm<<<(GG * OUTC + 255) / 256, 256, 0, stream>>>(readout, Wc, bc, out);
}

// Round 16
// 312.762 us; speedup vs baseline: 3.4717x; 3.4717x over previous
//
#include <hip/hip_runtime.h>

#define NN 100000
#define EE 1600000
#define GG 512
#define LL 5
#define HID 64
#define RCOLS (HID*LL)   // 320
#define OUTC 16
#define NGRP ((NN + 63) / 64)     // 1563
#define NBUCK ((NN + 255) / 256)  // 391 buckets of 256 nodes
#define BCAP 4864                 // bucket capacity: mean 4096 + 12 sigma

typedef unsigned int uint;
typedef unsigned short ushort;
typedef __attribute__((ext_vector_type(8))) short short8;
typedef __attribute__((ext_vector_type(4))) float f32x4;

__device__ __forceinline__ float bf2f(ushort u) {
    return __uint_as_float(((uint)u) << 16);
}
__device__ __forceinline__ ushort f2bf(float f) {
    uint u = __float_as_uint(f);
    u = (u + 0x7fffu + ((u >> 16) & 1u)) >> 16;   // round-to-nearest-even
    return (ushort)u;
}
__device__ __forceinline__ uint pack2(float a, float b) {
    return (uint)f2bf(a) | ((uint)f2bf(b) << 16);
}
__device__ __forceinline__ float lo16(uint p) { return __uint_as_float(p << 16); }
__device__ __forceinline__ float hi16(uint p) { return __uint_as_float(p & 0xffff0000u); }

// ================= bucketed CSR build, fixed-capacity buckets =================
__global__ __launch_bounds__(256) void init_bcur_kernel(int* __restrict__ bcur)
{
    int i = blockIdx.x * 256 + threadIdx.x;
    if (i < NBUCK) bcur[i] = i * BCAP;
}

__global__ __launch_bounds__(256) void binfill_kernel(
    const int* __restrict__ src, const int* __restrict__ dst,
    int* __restrict__ bcur, uint* __restrict__ bin)
{
    __shared__ int hcnt[NBUCK], hbase[NBUCK];
    const int tid = threadIdx.x;
    for (int b = tid; b < NBUCK; b += 256) hcnt[b] = 0;
    __syncthreads();
    const int chunk = (EE + gridDim.x - 1) / gridDim.x;
    const int e0 = blockIdx.x * chunk;
    const int e1 = (e0 + chunk < EE) ? e0 + chunk : EE;
    for (int e = e0 + tid; e < e1; e += 256)
        atomicAdd(&hcnt[dst[e] >> 8], 1);
    __syncthreads();
    for (int b = tid; b < NBUCK; b += 256) {
        int c = hcnt[b];
        hbase[b] = c ? atomicAdd(&bcur[b], c) : 0;
        hcnt[b] = 0;
    }
    __syncthreads();
    for (int e = e0 + tid; e < e1; e += 256) {
        int d = dst[e];
        int b = d >> 8;
        int off = atomicAdd(&hcnt[b], 1);
        bin[hbase[b] + off] = ((uint)src[e] << 8) | (uint)(d & 255);   // src<2^24
    }
}

__global__ __launch_bounds__(256) void bucket_csr_kernel(
    const uint* __restrict__ bin, const int* __restrict__ bcur,
    int* __restrict__ rowptr, int* __restrict__ rowend, int* __restrict__ col)
{
    __shared__ int h[256], s[256];
    const int b = blockIdx.x;
    const int tid = threadIdx.x;
    const int base = b * BCAP;
    const int cnt = bcur[b] - base;
    h[tid] = 0;
    __syncthreads();
    for (int i = tid; i < cnt; i += 256)
        atomicAdd(&h[bin[base + i] & 255], 1);
    __syncthreads();
    const int own = h[tid];
    s[tid] = own;
    __syncthreads();
    int val = own;
    for (int off = 1; off < 256; off <<= 1) {
        int other = (tid >= off) ? s[tid - off] : 0;
        __syncthreads();
        val += other;
        s[tid] = val;
        __syncthreads();
    }
    const int excl = val - own;
    const int node = b * 256 + tid;
    if (node < NN) {
        rowptr[node] = base + excl;
        rowend[node] = base + excl + own;
    }
    h[tid] = base + excl;      // per-node cursor
    __syncthreads();
    for (int i = tid; i < cnt; i += 256) {
        uint w = bin[base + i];
        int p = atomicAdd(&h[w & 255], 1);
        col[p] = (int)(w >> 8);
    }
}

// -------- prep: transposed bf16 weights, [c][72] padded rows, L1-resident at use --------
__global__ __launch_bounds__(256) void prep_w_kernel(
    const float* __restrict__ W2, const float* __restrict__ W1_r,
    ushort* __restrict__ w2t, ushort* __restrict__ w1nt)
{
    const int i = blockIdx.x * 256 + threadIdx.x;
    if (i < 5 * 4096) {
        int l = i >> 12, r = i & 4095, k = r >> 6, c = r & 63;
        w2t[l * 4608 + c * 72 + k] = f2bf(W2[l * 4096 + k * 64 + c]);
    }
    if (i < 4 * 4096) {
        int l = i >> 12, r = i & 4095, k = r >> 6, c = r & 63;
        w1nt[l * 4608 + c * 72 + k] = f2bf(W1_r[l * 4096 + k * 64 + c]);
    }
}

// ---------------- y0 = x @ W1_0  (fp32 [N,128] @ [128,64] -> bf16 [N,64]) ----------------
// mfma(A-frag,B-frag) = A·B^T, frags k-contiguous per lane; C/D col=lane&15, row=(lane>>4)*4+r.
__global__ __launch_bounds__(256) void ingemm_kernel(
    const float* __restrict__ x, const float* __restrict__ W1,
    ushort* __restrict__ Y0)
{
    __shared__ __align__(16) ushort W1t[64 * 136];   // W1^T [c][k], k=0..127, pad 136
    __shared__ __align__(16) ushort zA[4][16 * 72];

    for (int e = threadIdx.x; e < 64 * 128; e += 256) {
        int c = e & 63, k = e >> 6;
        W1t[c * 136 + k] = f2bf(W1[k * 64 + c]);
    }
    __syncthreads();

    const int lane = threadIdx.x & 63;
    const int wave = threadIdx.x >> 6;
    const int fr = lane & 15, fq = lane >> 4;
    ushort* zw = zA[wave];

    for (int grp = blockIdx.x; grp < NGRP; grp += gridDim.x) {
        const int base = grp * 64 + wave * 16;
        if (base >= NN) continue;

        short8 az[4];
        #pragma unroll
        for (int h = 0; h < 4; ++h) {
            const float* xp = x + (size_t)(base + fr) * 128 + h * 32 + fq * 8;
            float4 f0 = *(const float4*)xp;
            float4 f1 = *(const float4*)(xp + 4);
            short8 a;
            a[0] = (short)f2bf(f0.x); a[1] = (short)f2bf(f0.y);
            a[2] = (short)f2bf(f0.z); a[3] = (short)f2bf(f0.w);
            a[4] = (short)f2bf(f1.x); a[5] = (short)f2bf(f1.y);
            a[6] = (short)f2bf(f1.z); a[7] = (short)f2bf(f1.w);
            az[h] = a;
        }
        #pragma unroll
        for (int t = 0; t < 4; ++t) {
            f32x4 acc = {0.f, 0.f, 0.f, 0.f};
            #pragma unroll
            for (int h = 0; h < 4; ++h) {
                short8 bw = *(const short8*)&W1t[(t * 16 + fr) * 136 + h * 32 + fq * 8];
                acc = __builtin_amdgcn_mfma_f32_16x16x32_bf16(az[h], bw, acc, 0, 0, 0);
            }
            #pragma unroll
            for (int r = 0; r < 4; ++r)
                zw[(fq * 4 + r) * 72 + t * 16 + fr] = f2bf(acc[r]);
        }
        #pragma unroll 4
        for (int i = 0; i < 16; ++i)
            Y0[(size_t)(base + i) * 64 + lane] = zw[i * 72 + lane];
    }
}

// ------- fused layer on Y = h@W1 (bf16 [NN+1,64], row NN == zeros):
//   gather t = (1+eps)*Y[row] + sum Y[neigh]   (linear-commute: this IS z@W1)
//   v1 = relu(t*sa+sh); v2 = relu((v1@W2)*sb+shb); pool; Ynext = v2 @ W1next
// R9 configuration — empirically the constrained optimum (R10-R15 all refuted):
// 16 rows/wave, 4-wave blocks, LDS-staged idx, uint2 dual-row gather,
// launch_bounds(256,7) -> VGPR 36, no spill, ~52% occupancy.
template<bool LAST>
__global__ __launch_bounds__(256, 7) void gin_layer_kernel(
    const ushort* __restrict__ Y,
    const int* __restrict__ rowptr, const int* __restrict__ rowend,
    const int* __restrict__ col,
    const float* __restrict__ eps_arr, int l,
    const float* __restrict__ b1,
    const ushort* __restrict__ w2t,    // bf16 [64][72] W2^T
    const float* __restrict__ b2,
    const float* __restrict__ g_a, const float* __restrict__ be_a,
    const float* __restrict__ m_a, const float* __restrict__ v_a,
    const float* __restrict__ g_b, const float* __restrict__ be_b,
    const float* __restrict__ m_b, const float* __restrict__ v_b,
    const ushort* __restrict__ w1nt,   // bf16 [64][72] W1next^T (unused if LAST)
    const int* __restrict__ batch,
    ushort* __restrict__ Ynext,
    float* __restrict__ readout,
    int layer_off)
{
    __shared__ __align__(16) ushort zA[4][16 * 72];   // per-wave tile [r][k]
    __shared__ float2 bnA[64], bnB[64];
    __shared__ __align__(16) int idxs[4][144];        // [72 rowA | 72 rowB], pads=NN

    if (threadIdx.x < 64) {
        int c = threadIdx.x;
        float sa = g_a[c] * rsqrtf(v_a[c] + 1e-5f);
        float sb = g_b[c] * rsqrtf(v_b[c] + 1e-5f);
        bnA[c] = make_float2(sa, be_a[c] + (b1[c] - m_a[c]) * sa);
        bnB[c] = make_float2(sb, be_b[c] + (b2[c] - m_b[c]) * sb);
    }
    const float eps_l = 1.0f + eps_arr[l];
    __syncthreads();

    const int lane = threadIdx.x & 63;
    const int wave = threadIdx.x >> 6;
    const int fr = lane & 15, fq = lane >> 4;
    const int c4 = (lane & 15) * 4;        // channel base (4 channels per lane)
    const int sl = (lane >> 4) & 1;        // neighbor slot within half
    const int rb = (lane >> 5) * 72;       // idw base: 0=row A half, 72=row B half
    ushort* zw = zA[wave];
    int* idw = idxs[wave];
    const float2 ba0 = bnA[c4], ba1 = bnA[c4 + 1], ba2 = bnA[c4 + 2], ba3 = bnA[c4 + 3];

    for (int grp = blockIdx.x; grp < NGRP; grp += gridDim.x) {
        const int base = grp * 64 + wave * 16;
        if (base >= NN) continue;      // NN%16==0: waves all-valid or all-idle

        // ---- phase 1: gather pairs of rows; 4 uint2 loads (16 neighbor-rows) in flight ----
        for (int i = 0; i < 16; i += 2) {
            const int rowA = base + i, rowB = base + i + 1;
            int ja = rowptr[rowA];
            const int reA = rowend[rowA];
            int jb = reA;                       // rowB contiguous after rowA (same bucket)
            const int reB = rowend[rowB];
            float a0 = 0.f, a1 = 0.f, a2 = 0.f, a3 = 0.f;
            while (ja < reA || jb < reB) {
                int cntA = reA - ja; cntA = cntA > 64 ? 64 : cntA;
                int cntB = reB - jb; cntB = cntB > 64 ? 64 : cntB;
                {
                    int ia = ja + (lane < cntA ? lane : 0);
                    int ca = col[ia];
                    idw[lane] = (lane < cntA) ? ca : NN;
                    int ib = jb + (lane < cntB ? lane : 0);
                    int cb = col[ib];
                    idw[72 + lane] = (lane < cntB) ? cb : NN;
                    if (lane < 8) { idw[64 + lane] = NN; idw[136 + lane] = NN; }
                }
                const int niA = (cntA + 1) >> 1, niB = (cntB + 1) >> 1;
                const int ni = niA > niB ? niA : niB;
                for (int t = 0; t < ni; t += 4) {
                    int r0 = idw[rb + (t + 0) * 2 + sl];
                    int r1 = idw[rb + (t + 1) * 2 + sl];
                    int r2 = idw[rb + (t + 2) * 2 + sl];
                    int r3 = idw[rb + (t + 3) * 2 + sl];
                    uint2 w0 = *(const uint2*)&Y[(size_t)r0 * 64 + c4];
                    uint2 w1 = *(const uint2*)&Y[(size_t)r1 * 64 + c4];
                    uint2 w2 = *(const uint2*)&Y[(size_t)r2 * 64 + c4];
                    uint2 w3 = *(const uint2*)&Y[(size_t)r3 * 64 + c4];
                    a0 += (lo16(w0.x) + lo16(w1.x)) + (lo16(w2.x) + lo16(w3.x));
                    a1 += (hi16(w0.x) + hi16(w1.x)) + (hi16(w2.x) + hi16(w3.x));
                    a2 += (lo16(w0.y) + lo16(w1.y)) + (lo16(w2.y) + lo16(w3.y));
                    a3 += (hi16(w0.y) + hi16(w1.y)) + (hi16(w2.y) + hi16(w3.y));
                }
                ja += cntA; jb += cntB;
            }
            // combine the two neighbor-slots within each half
            a0 += __shfl_xor(a0, 16); a1 += __shfl_xor(a1, 16);
            a2 += __shfl_xor(a2, 16); a3 += __shfl_xor(a3, 16);
            // self row + BN + ReLU
            const int myrow = (lane < 32) ? rowA : rowB;
            uint2 wr = *(const uint2*)&Y[(size_t)myrow * 64 + c4];
            a0 += eps_l * lo16(wr.x); a1 += eps_l * hi16(wr.x);
            a2 += eps_l * lo16(wr.y); a3 += eps_l * hi16(wr.y);
            float z0 = fmaxf(a0 * ba0.x + ba0.y, 0.f);
            float z1 = fmaxf(a1 * ba1.x + ba1.y, 0.f);
            float z2 = fmaxf(a2 * ba2.x + ba2.y, 0.f);
            float z3 = fmaxf(a3 * ba3.x + ba3.y, 0.f);
            if ((lane & 31) < 16) {    // lanes 0-15 write rowA, 32-47 write rowB
                uint2 pz;
                pz.x = pack2(z0, z1);
                pz.y = pack2(z2, z3);
                *(uint2*)&zw[(i + (lane >> 5)) * 72 + c4] = pz;
            }
        }

        // ---- phase 2: v2 = relu(bnB(v1 @ W2)) -> zw (B-frags from L1-resident global) ----
        short8 a2f[2];
        a2f[0] = *(const short8*)&zw[fr * 72 + fq * 8];
        a2f[1] = *(const short8*)&zw[fr * 72 + 32 + fq * 8];
        #pragma unroll
        for (int t = 0; t < 4; ++t) {
            f32x4 acc = {0.f, 0.f, 0.f, 0.f};
            short8 bw0 = *(const short8*)&w2t[(t * 16 + fr) * 72 + fq * 8];
            short8 bw1 = *(const short8*)&w2t[(t * 16 + fr) * 72 + 32 + fq * 8];
            acc = __builtin_amdgcn_mfma_f32_16x16x32_bf16(a2f[0], bw0, acc, 0, 0, 0);
            acc = __builtin_amdgcn_mfma_f32_16x16x32_bf16(a2f[1], bw1, acc, 0, 0, 0);
            float2 bn = bnB[t * 16 + fr];
            #pragma unroll
            for (int r = 0; r < 4; ++r) {
                float v = fmaxf(acc[r] * bn.x + bn.y, 0.f);
                zw[(fq * 4 + r) * 72 + t * 16 + fr] = f2bf(v);
            }
        }

        // ---- phase 3: run-length-reduced readout atomics ----
        {
            int curg = batch[base];
            float racc = 0.f;
            #pragma unroll 4
            for (int i = 0; i < 16; ++i) {
                const float v = bf2f(zw[i * 72 + lane]);
                const int g = batch[base + i];
                if (g != curg) {   // wave-uniform (batch sorted)
                    unsafeAtomicAdd(readout + (size_t)curg * RCOLS + layer_off + lane, racc);
                    curg = g;
                    racc = v;
                } else {
                    racc += v;
                }
            }
            unsafeAtomicAdd(readout + (size_t)curg * RCOLS + layer_off + lane, racc);
        }

        // ---- phase 4: Ynext = v2 @ W1next; coalesced row stores ----
        if constexpr (!LAST) {
            short8 a3f[2];
            a3f[0] = *(const short8*)&zw[fr * 72 + fq * 8];
            a3f[1] = *(const short8*)&zw[fr * 72 + 32 + fq * 8];
            #pragma unroll
            for (int t = 0; t < 4; ++t) {
                f32x4 acc = {0.f, 0.f, 0.f, 0.f};
                short8 bw0 = *(const short8*)&w1nt[(t * 16 + fr) * 72 + fq * 8];
                short8 bw1 = *(const short8*)&w1nt[(t * 16 + fr) * 72 + 32 + fq * 8];
                acc = __builtin_amdgcn_mfma_f32_16x16x32_bf16(a3f[0], bw0, acc, 0, 0, 0);
                acc = __builtin_amdgcn_mfma_f32_16x16x32_bf16(a3f[1], bw1, acc, 0, 0, 0);
                #pragma unroll
                for (int r = 0; r < 4; ++r)
                    zw[(fq * 4 + r) * 72 + t * 16 + fr] = f2bf(acc[r]);
            }
            #pragma unroll 4
            for (int i = 0; i < 16; ++i)
                Ynext[(size_t)(base + i) * 64 + lane] = zw[i * 72 + lane];
        }
    }
}

// ---------------- final graph-level GEMM: [G,320] @ [320,16] + bc ----------------
__global__ __launch_bounds__(256) void final_gemm(
    const float* __restrict__ R, const float* __restrict__ Wc,
    const float* __restrict__ bc, float* __restrict__ out)
{
    const int tid = blockIdx.x * 256 + threadIdx.x;
    if (tid >= GG * OUTC) return;
    const int g = tid >> 4;
    const int o = tid & 15;
    float acc = bc[o];
    const float* r = R + (size_t)g * RCOLS;
    #pragma unroll 8
    for (int k = 0; k < RCOLS; ++k)
        acc += r[k] * Wc[k * OUTC + o];
    out[tid] = acc;
}

extern "C" void kernel_launch(void* const* d_in, const int* in_sizes, int n_in,
                              void* d_out, int out_size, void* d_ws, size_t ws_size,
                              hipStream_t stream)
{
    const float* x    = (const float*)d_in[0];
    const int*   ei   = (const int*)d_in[1];
    const int*   batch= (const int*)d_in[2];
    const float* eps  = (const float*)d_in[3];
    const float* W1_0 = (const float*)d_in[4];
    const float* b1_0 = (const float*)d_in[5];
    const float* W1_r = (const float*)d_in[6];
    const float* b1_r = (const float*)d_in[7];
    const float* g_a  = (const float*)d_in[8];
    const float* be_a = (const float*)d_in[9];
    const float* m_a  = (const float*)d_in[10];
    const float* v_a  = (const float*)d_in[11];
    const float* W2   = (const float*)d_in[12];
    const float* b2   = (const float*)d_in[13];
    const float* g_b  = (const float*)d_in[14];
    const float* be_b = (const float*)d_in[15];
    const float* m_b  = (const float*)d_in[16];
    const float* v_b  = (const float*)d_in[17];
    const float* Wc   = (const float*)d_in[18];
    const float* bc   = (const float*)d_in[19];
    float* out = (float*)d_out;

    const int* src = ei;
    const int* dst = ei + EE;

    // workspace layout (bytes); y buffers have NN+1 rows (row NN = zeros, gather pad target)
    char* ws = (char*)d_ws;
    int*    rowptr  = (int*)(ws);                        // N*4
    int*    rowend  = (int*)(ws + 524288);               // N*4
    int*    bcur    = (int*)(ws + 1048576);              // NBUCK*4
    int*    col     = (int*)(ws + 1572864);              // NBUCK*BCAP*4 (+slack)
    uint*   bin     = (uint*)(ws + 9437184);             // NBUCK*BCAP*4
    ushort* y_a     = (ushort*)(ws + 17301504);          // (N+1)*64*2
    ushort* y_b     = (ushort*)(ws + 30212096);          // (N+1)*64*2
    float*  readout = (float*)(ws + 43122688);           // 640KB
    ushort* w2t_g   = (ushort*)(ws + 43778048);          // 5*64*72*2
    ushort* w1nt_g  = (ushort*)(ws + 43824128);          // 4*64*72*2

    hipMemsetAsync(readout, 0, (size_t)GG * RCOLS * 4, stream);
    hipMemsetAsync(y_a + (size_t)NN * 64, 0, 128, stream);   // zero pad-row
    hipMemsetAsync(y_b + (size_t)NN * 64, 0, 128, stream);

    init_bcur_kernel<<<(NBUCK + 255) / 256, 256, 0, stream>>>(bcur);
    prep_w_kernel<<<80, 256, 0, stream>>>(W2, W1_r, w2t_g, w1nt_g);
    ingemm_kernel<<<NGRP, 256, 0, stream>>>(x, W1_0, y_a);   // y0 = x @ W1_0
    binfill_kernel<<<256, 256, 0, stream>>>(src, dst, bcur, bin);
    bucket_csr_kernel<<<NBUCK, 256, 0, stream>>>(bin, bcur, rowptr, rowend, col);

    ushort* y_cur = y_a;
    ushort* y_nxt = y_b;

    for (int l = 0; l < LL; ++l) {
        const float* b1 = (l == 0) ? b1_0 : (b1_r + (size_t)(l - 1) * 64);
        const int off = l * 64;
        const ushort* w2t  = w2t_g + (size_t)l * 4608;
        const ushort* w1nt = (l < LL - 1) ? (w1nt_g + (size_t)l * 4608) : w1nt_g;
        if (l < LL - 1) {
            gin_layer_kernel<false><<<NGRP, 256, 0, stream>>>(
                y_cur, rowptr, rowend, col, eps, l, b1,
                w2t, b2 + off,
                g_a + off, be_a + off, m_a + off, v_a + off,
                g_b + off, be_b + off, m_b + off, v_b + off,
                w1nt, batch, y_nxt, readout, off);
        } else {
            gin_layer_kernel<true><<<NGRP, 256, 0, stream>>>(
                y_cur, rowptr, rowend, col, eps, l, b1,
                w2t, b2 + off,
                g_a + off, be_a + off, m_a + off, v_a + off,
                g_b + off, be_b + off, m_b + off, v_b + off,
                w1nt, batch, y_nxt, readout, off);
        }
        ushort* t = y_cur; y_cur = y_nxt; y_nxt = t;
    }

    final_gemm<<<(GG * OUTC + 255) / 256, 256, 0, stream>>>(readout, Wc, bc, out);
}